// Round 6
// baseline (530.569 us; speedup 1.0000x reference)
//
#include <hip/hip_runtime.h>

// Resample 48k -> 10k: up=5, down=24, 481-tap FIR.
// y[5k+d] = sum_{c,u} T[c*40+d*8+u] * x[24k-48+8c+u],  c=0..14, u=0..7
// T[c*40+d*8+u] = 5*h[24d+480-5*(8c+u)]  (wave-uniform -> SGPR s_load)
//
// R6: NO LDS, NO BARRIER. Adjacent-lane windows overlap 75% -> L1 does the
// reuse (tile ~30KB/CU fits 32KB L1). Each thread: 2 consecutive k's
// (10 outputs), 36 float4 global loads, 1200 FMAs in 10 independent chains,
// 5 float2 contiguous stores. __launch_bounds__(256,8) -> <=64 VGPR ->
// 8 waves/SIMD = 32 waves/CU, fully independent (no intra-block coupling).
// k+1 shares the k window: chunk c feeds acc_k via T[c] and acc_{k+1} via T[c-3].

#define NIN   1440000
#define NOUTR 300000
#define NROWS 32
#define KTOT  60000
#define KPT   2
#define BKT   (256 * KPT)               // 512 k per block
#define NBX   ((KTOT + BKT - 1) / BKT)  // 118 (last block partial: 96 k)
#define TAPN  600

__global__ void prep_taps_kernel(const float* __restrict__ h, float* __restrict__ T) {
    int i = blockIdx.x * blockDim.x + threadIdx.x;
    if (i < TAPN) {
        int u  = i & 7;
        int d  = (i >> 3) % 5;
        int c  = i / 40;
        int t  = 24 * d + 480 - 5 * (c * 8 + u);
        T[i] = (t >= 0 && t <= 480) ? h[t] * 5.0f : 0.0f;
    }
}

__global__ __launch_bounds__(256, 8) void resample_kernel(
    const float* __restrict__ x, const float* __restrict__ T, float* __restrict__ y)
{
    const int tid = threadIdx.x;
    const int row = blockIdx.y;
    const int k   = blockIdx.x * BKT + 2 * tid;     // this thread: k, k+1
    const float* __restrict__ xr = x + (size_t)row * NIN;

    float a0=0.f,a1=0.f,a2=0.f,a3=0.f,a4=0.f;       // y[5k+d]
    float b0=0.f,b1=0.f,b2=0.f,b3=0.f,b4=0.f;       // y[5(k+1)+d]

    const int g0 = 24 * k - 48;                     // 16B-aligned (mult of 4 floats)

    if (blockIdx.x != 0 && blockIdx.x != NBX - 1) {
        // interior fast path: unguarded float4 loads
        const float* __restrict__ gp = xr + g0;
        #pragma unroll
        for (int c = 0; c < 18; ++c) {
            const float4 va = *reinterpret_cast<const float4*>(gp + 8 * c);
            const float4 vb = *reinterpret_cast<const float4*>(gp + 8 * c + 4);
            const float xv[8] = {va.x, va.y, va.z, va.w, vb.x, vb.y, vb.z, vb.w};
            if (c < 15) {
                const float* __restrict__ tp = T + c * 40;   // uniform -> s_load
                #pragma unroll
                for (int u = 0; u < 8; ++u) {
                    a0 += tp[     u] * xv[u];
                    a1 += tp[ 8 + u] * xv[u];
                    a2 += tp[16 + u] * xv[u];
                    a3 += tp[24 + u] * xv[u];
                    a4 += tp[32 + u] * xv[u];
                }
            }
            if (c >= 3) {
                const float* __restrict__ tq = T + (c - 3) * 40;
                #pragma unroll
                for (int u = 0; u < 8; ++u) {
                    b0 += tq[     u] * xv[u];
                    b1 += tq[ 8 + u] * xv[u];
                    b2 += tq[16 + u] * xv[u];
                    b3 += tq[24 + u] * xv[u];
                    b4 += tq[32 + u] * xv[u];
                }
            }
        }
        float* __restrict__ yr = y + (size_t)row * NOUTR + (size_t)5 * k;
        *reinterpret_cast<float2*>(yr + 0) = make_float2(a0, a1);
        *reinterpret_cast<float2*>(yr + 2) = make_float2(a2, a3);
        *reinterpret_cast<float2*>(yr + 4) = make_float2(a4, b0);
        *reinterpret_cast<float2*>(yr + 6) = make_float2(b1, b2);
        *reinterpret_cast<float2*>(yr + 8) = make_float2(b3, b4);
    } else {
        // edge blocks: guarded loads, guarded per-k stores
        if (k >= KTOT) return;
        #pragma unroll
        for (int c = 0; c < 18; ++c) {
            float xv[8];
            #pragma unroll
            for (int u = 0; u < 8; ++u) {
                const int g = g0 + 8 * c + u;
                xv[u] = ((unsigned)g < NIN) ? xr[g] : 0.0f;
            }
            if (c < 15) {
                const float* __restrict__ tp = T + c * 40;
                #pragma unroll
                for (int u = 0; u < 8; ++u) {
                    a0 += tp[     u] * xv[u];
                    a1 += tp[ 8 + u] * xv[u];
                    a2 += tp[16 + u] * xv[u];
                    a3 += tp[24 + u] * xv[u];
                    a4 += tp[32 + u] * xv[u];
                }
            }
            if (c >= 3) {
                const float* __restrict__ tq = T + (c - 3) * 40;
                #pragma unroll
                for (int u = 0; u < 8; ++u) {
                    b0 += tq[     u] * xv[u];
                    b1 += tq[ 8 + u] * xv[u];
                    b2 += tq[16 + u] * xv[u];
                    b3 += tq[24 + u] * xv[u];
                    b4 += tq[32 + u] * xv[u];
                }
            }
        }
        float* __restrict__ yr = y + (size_t)row * NOUTR + (size_t)5 * k;
        yr[0]=a0; yr[1]=a1; yr[2]=a2; yr[3]=a3; yr[4]=a4;
        if (k + 1 < KTOT) {
            yr[5]=b0; yr[6]=b1; yr[7]=b2; yr[8]=b3; yr[9]=b4;
        }
    }
}

extern "C" void kernel_launch(void* const* d_in, const int* in_sizes, int n_in,
                              void* d_out, int out_size, void* d_ws, size_t ws_size,
                              hipStream_t stream) {
    const float* x = (const float*)d_in[0];
    const float* h = (const float*)d_in[1];   // 481 taps
    float* y = (float*)d_out;                 // 32 x 300000 f32
    float* T = (float*)d_ws;                  // 600 floats of scratch

    prep_taps_kernel<<<3, 256, 0, stream>>>(h, T);
    dim3 grid(NBX, NROWS);                    // 118 x 32
    resample_kernel<<<grid, 256, 0, stream>>>(x, T, y);
}

// Round 7
// 57.739 us; speedup vs baseline: 9.1892x; 9.1892x over previous
//
#include <hip/hip_runtime.h>

// Resample 48k -> 10k: up=5, down=24, 481-tap FIR.
// y[5k+d] = sum_{c=0..14,u=0..7} T[c*40+d*8+u] * x[24k-48+8c+u]
// T[c*40+d*8+u] = 5*h[24d+480-5*(8c+u)]  (wave-uniform -> SGPR s_load)
//
// R7: inner product via v_pk_fma_f32 (VOP3P packed fp32 — the only path to
// the 157 TF fp32 rate). Even/odd partial-sum form:
//   acc_d.xy += (t[u],t[u+1]) * (x[u],x[u+1]);  y_d = acc.x + acc.y
// Tap pairs are wave-uniform -> SGPR pair as VOP3P src0 (1 scalar operand).
// x pairs come straight from conflict-free ds_read_b64 -> no extraction VALU.
// Cuts per-k VALU ~700 -> ~290 instrs.
//
// LDS: pad-2-per-8 swizzle (m = e + (e>>3)*2), 31.2 kB -> 5 blocks/CU.
//   window chunk e0=24t+8c -> m0=30t+10c, 8 floats contiguous -> 4x b64,
//   bank-pair (15t+5c+j) mod 16, 15 coprime 16 -> conflict-free.

#define NIN   1440000
#define NOUTR 300000
#define NROWS 32
#define KTOT  60000
#define BK    256
#define NBX   ((KTOT + BK - 1) / BK)   // 235
#define TILE  6240                     // 24*255 + 120
#define NV4   (TILE / 4)
#define LDSN  (TILE + (TILE / 8) * 2)  // 7800 floats = 31.2 kB
#define TAPN  600

__global__ void prep_taps_kernel(const float* __restrict__ h, float* __restrict__ T) {
    int i = blockIdx.x * blockDim.x + threadIdx.x;
    if (i < TAPN) {
        int u = i & 7;
        int d = (i >> 3) % 5;
        int c = i / 40;
        int t = 24 * d + 480 - 5 * (c * 8 + u);
        T[i] = (t >= 0 && t <= 480) ? h[t] * 5.0f : 0.0f;
    }
}

__global__ __launch_bounds__(256) void resample_kernel(
    const float* __restrict__ x, const float* __restrict__ T, float* __restrict__ y)
{
    __shared__ float lds[LDSN];
    const int tid = threadIdx.x;
    const int row = blockIdx.y;
    const int k0  = blockIdx.x * BK;
    const float* __restrict__ xr = x + (size_t)row * NIN;
    const int g0 = 24 * k0 - 48;

    // Stage x tile with pad-2-per-8 swizzle.
    if (g0 >= 0 && g0 + TILE <= NIN) {           // interior fast path
        for (int i4 = tid; i4 < NV4; i4 += 256) {
            const int e = i4 * 4;
            const float4 v = *reinterpret_cast<const float4*>(xr + g0 + e);
            const int m = e + ((e >> 3) << 1);
            *reinterpret_cast<float2*>(&lds[m])     = make_float2(v.x, v.y);
            *reinterpret_cast<float2*>(&lds[m + 2]) = make_float2(v.z, v.w);
        }
    } else {                                      // first/last blocks only
        for (int i4 = tid; i4 < NV4; i4 += 256) {
            const int e = i4 * 4;
            const int g = g0 + e;
            float4 v;
            v.x = ((unsigned)(g + 0) < NIN) ? xr[g + 0] : 0.0f;
            v.y = ((unsigned)(g + 1) < NIN) ? xr[g + 1] : 0.0f;
            v.z = ((unsigned)(g + 2) < NIN) ? xr[g + 2] : 0.0f;
            v.w = ((unsigned)(g + 3) < NIN) ? xr[g + 3] : 0.0f;
            const int m = e + ((e >> 3) << 1);
            *reinterpret_cast<float2*>(&lds[m])     = make_float2(v.x, v.y);
            *reinterpret_cast<float2*>(&lds[m + 2]) = make_float2(v.z, v.w);
        }
    }
    __syncthreads();

    float2 acc[5];
    #pragma unroll
    for (int d = 0; d < 5; ++d) acc[d] = make_float2(0.f, 0.f);

    const int base = 30 * tid;
    #pragma unroll
    for (int c = 0; c < 15; ++c) {
        const int m0 = base + 10 * c;
        const float2 xv0 = *reinterpret_cast<const float2*>(&lds[m0]);
        const float2 xv1 = *reinterpret_cast<const float2*>(&lds[m0 + 2]);
        const float2 xv2 = *reinterpret_cast<const float2*>(&lds[m0 + 4]);
        const float2 xv3 = *reinterpret_cast<const float2*>(&lds[m0 + 6]);
        #pragma unroll
        for (int d = 0; d < 5; ++d) {
            // compile-time skip of all-zero tap groups (c,d constants)
            if (24 * d + 480 - 40 * c >= 0 && 24 * d + 445 - 40 * c <= 480) {
                const float2* __restrict__ tp =
                    reinterpret_cast<const float2*>(T + c * 40 + d * 8);
                const float2 t0 = tp[0], t1 = tp[1], t2 = tp[2], t3 = tp[3];
                asm("v_pk_fma_f32 %0, %1, %2, %0" : "+v"(acc[d]) : "s"(t0), "v"(xv0));
                asm("v_pk_fma_f32 %0, %1, %2, %0" : "+v"(acc[d]) : "s"(t1), "v"(xv1));
                asm("v_pk_fma_f32 %0, %1, %2, %0" : "+v"(acc[d]) : "s"(t2), "v"(xv2));
                asm("v_pk_fma_f32 %0, %1, %2, %0" : "+v"(acc[d]) : "s"(t3), "v"(xv3));
            }
        }
    }

    const int k = k0 + tid;
    if (k < KTOT) {
        float* __restrict__ yr = y + (size_t)row * NOUTR + (size_t)5 * k;
        yr[0] = acc[0].x + acc[0].y;
        yr[1] = acc[1].x + acc[1].y;
        yr[2] = acc[2].x + acc[2].y;
        yr[3] = acc[3].x + acc[3].y;
        yr[4] = acc[4].x + acc[4].y;
    }
}

extern "C" void kernel_launch(void* const* d_in, const int* in_sizes, int n_in,
                              void* d_out, int out_size, void* d_ws, size_t ws_size,
                              hipStream_t stream) {
    const float* x = (const float*)d_in[0];
    const float* h = (const float*)d_in[1];   // 481 taps
    float* y = (float*)d_out;                 // 32 x 300000 f32
    float* T = (float*)d_ws;                  // 600 floats of scratch

    prep_taps_kernel<<<3, 256, 0, stream>>>(h, T);
    dim3 grid(NBX, NROWS);                    // 235 x 32
    resample_kernel<<<grid, 256, 0, stream>>>(x, T, y);
}

// Round 8
// 55.249 us; speedup vs baseline: 9.6032x; 1.0451x over previous
//
#include <hip/hip_runtime.h>

// Resample 48k -> 10k: up=5, down=24, 481-tap FIR.
// y[5k+d] = sum_{c=0..14,u=0..7} T[c*40+d*8+u] * x[24k-48+8c+u]
// T[c*40+d*8+u] = 5*h[24d+480-5*(8c+u)]  (wave-uniform -> SGPR s_load)
//
// R8: 1-WAVE BLOCKS to break the convoy effect. R3/R7 fit a zero-overlap
// sum model (VALU+DS+HBM ~= dur): 256-thread blocks march in lockstep
// {HBM burst -> barrier -> DS/VALU burst}, starving pipes alternately.
// 64-thread blocks have no cross-wave coupling; ~19 independent waves/CU
// drift out of phase -> all pipes stream concurrently.
// Inner loop unchanged from R7: conflict-free pad-2/8 b64 window reads +
// wave-uniform SGPR tap pairs feeding v_pk_fma_f32.

#define NIN   1440000
#define NOUTR 300000
#define NROWS 32
#define KTOT  60000
#define BKW   64                        // k per block = 1 wave
#define NBX   ((KTOT + BKW - 1) / BKW)  // 938 (last block: 32 valid k)
#define TILE  1632                      // 24*63 + 120
#define NV4   (TILE / 4)                // 408 float4s = 6*64 + 24
#define LDSN  (TILE + (TILE / 8) * 2)   // 2040 floats = 8160 B
#define TAPN  600

__global__ void prep_taps_kernel(const float* __restrict__ h, float* __restrict__ T) {
    int i = blockIdx.x * blockDim.x + threadIdx.x;
    if (i < TAPN) {
        int u = i & 7;
        int d = (i >> 3) % 5;
        int c = i / 40;
        int t = 24 * d + 480 - 5 * (c * 8 + u);
        T[i] = (t >= 0 && t <= 480) ? h[t] * 5.0f : 0.0f;
    }
}

__global__ __launch_bounds__(64, 8) void resample_kernel(
    const float* __restrict__ x, const float* __restrict__ T, float* __restrict__ y)
{
    __shared__ float lds[LDSN];
    const int tid = threadIdx.x;            // 0..63
    const int row = blockIdx.y;
    const int k0  = blockIdx.x * BKW;
    const float* __restrict__ xr = x + (size_t)row * NIN;
    const int g0 = 24 * k0 - 48;            // multiple of 4 -> 16B-aligned

    // Stage private wave tile with pad-2-per-8 swizzle (m = e + (e>>3)*2).
    if (g0 >= 0 && g0 + TILE <= NIN) {      // interior fast path
        #pragma unroll
        for (int j = 0; j < 7; ++j) {
            const int i4 = tid + 64 * j;
            if (j < 6 || i4 < NV4) {
                const int e = i4 * 4;
                const float4 v = *reinterpret_cast<const float4*>(xr + g0 + e);
                const int m = e + ((e >> 3) << 1);
                *reinterpret_cast<float2*>(&lds[m])     = make_float2(v.x, v.y);
                *reinterpret_cast<float2*>(&lds[m + 2]) = make_float2(v.z, v.w);
            }
        }
    } else {                                 // first/last blocks only
        #pragma unroll
        for (int j = 0; j < 7; ++j) {
            const int i4 = tid + 64 * j;
            if (j < 6 || i4 < NV4) {
                const int e = i4 * 4;
                const int g = g0 + e;
                float4 v;
                v.x = ((unsigned)(g + 0) < NIN) ? xr[g + 0] : 0.0f;
                v.y = ((unsigned)(g + 1) < NIN) ? xr[g + 1] : 0.0f;
                v.z = ((unsigned)(g + 2) < NIN) ? xr[g + 2] : 0.0f;
                v.w = ((unsigned)(g + 3) < NIN) ? xr[g + 3] : 0.0f;
                const int m = e + ((e >> 3) << 1);
                *reinterpret_cast<float2*>(&lds[m])     = make_float2(v.x, v.y);
                *reinterpret_cast<float2*>(&lds[m + 2]) = make_float2(v.z, v.w);
            }
        }
    }
    __syncthreads();                         // 1-wave block: near-free

    float2 acc[5];
    #pragma unroll
    for (int d = 0; d < 5; ++d) acc[d] = make_float2(0.f, 0.f);

    const int base = 30 * tid;               // swizzled window start (float2-even)
    #pragma unroll
    for (int c = 0; c < 15; ++c) {
        const int m0 = base + 10 * c;
        const float2 xv0 = *reinterpret_cast<const float2*>(&lds[m0]);
        const float2 xv1 = *reinterpret_cast<const float2*>(&lds[m0 + 2]);
        const float2 xv2 = *reinterpret_cast<const float2*>(&lds[m0 + 4]);
        const float2 xv3 = *reinterpret_cast<const float2*>(&lds[m0 + 6]);
        #pragma unroll
        for (int d = 0; d < 5; ++d) {
            // compile-time skip of all-zero tap groups (c,d constants)
            if (24 * d + 480 - 40 * c >= 0 && 24 * d + 445 - 40 * c <= 480) {
                const float2* __restrict__ tp =
                    reinterpret_cast<const float2*>(T + c * 40 + d * 8);
                const float2 t0 = tp[0], t1 = tp[1], t2 = tp[2], t3 = tp[3];
                asm("v_pk_fma_f32 %0, %1, %2, %0" : "+v"(acc[d]) : "s"(t0), "v"(xv0));
                asm("v_pk_fma_f32 %0, %1, %2, %0" : "+v"(acc[d]) : "s"(t1), "v"(xv1));
                asm("v_pk_fma_f32 %0, %1, %2, %0" : "+v"(acc[d]) : "s"(t2), "v"(xv2));
                asm("v_pk_fma_f32 %0, %1, %2, %0" : "+v"(acc[d]) : "s"(t3), "v"(xv3));
            }
        }
    }

    const int k = k0 + tid;
    if (k < KTOT) {
        float* __restrict__ yr = y + (size_t)row * NOUTR + (size_t)5 * k;
        yr[0] = acc[0].x + acc[0].y;
        yr[1] = acc[1].x + acc[1].y;
        yr[2] = acc[2].x + acc[2].y;
        yr[3] = acc[3].x + acc[3].y;
        yr[4] = acc[4].x + acc[4].y;
    }
}

extern "C" void kernel_launch(void* const* d_in, const int* in_sizes, int n_in,
                              void* d_out, int out_size, void* d_ws, size_t ws_size,
                              hipStream_t stream) {
    const float* x = (const float*)d_in[0];
    const float* h = (const float*)d_in[1];   // 481 taps
    float* y = (float*)d_out;                 // 32 x 300000 f32
    float* T = (float*)d_ws;                  // 600 floats of scratch

    prep_taps_kernel<<<3, 256, 0, stream>>>(h, T);
    dim3 grid(NBX, NROWS);                    // 938 x 32 one-wave blocks
    resample_kernel<<<grid, 64, 0, stream>>>(x, T, y);
}